// Round 13
// baseline (123.814 us; speedup 1.0000x reference)
//
#include <hip/hip_runtime.h>
#include <hip/hip_fp16.h>

#define BB 4
#define HH 128
#define WW 128
#define CC 32
#define OH 120
#define OW 120
#define KT 25
#define OFFC 100
#define FF 64
#define NPX 32
#define NTHREADS 512

typedef __attribute__((ext_vector_type(8))) short    s16x8;
typedef __attribute__((ext_vector_type(8))) _Float16 f16x8;
typedef __attribute__((ext_vector_type(2))) _Float16 h2;
typedef __attribute__((ext_vector_type(4))) float    f32x4;

// d_ws layout (short elements, fp16 bits):
//   WB:  [25 taps][7 n][64 lane][8]   89,600   (offset-conv weights, B-frag)
//   WD:  [4 n][25 taps][64 lane][8]   51,200   (dcn weights, B-frag)
//   V16: f16 volume [B][H][W][C]   2,097,152
#define WB_ELEMS   (KT * 7 * 64 * 8)
#define WD_ELEMS   (4 * KT * 64 * 8)
#define VOL_UNITS  (BB * HH * WW * CC / 8)      // 262,144 8-elem units
#define VOL16_OFF  (WB_ELEMS + WD_ELEMS)

__device__ __forceinline__ short f2h(float x) {
    _Float16 h = (_Float16)x;
    return __builtin_bit_cast(short, h);
}
__device__ __forceinline__ float h2f(short x) {
    return (float)__builtin_bit_cast(_Float16, x);
}

// ---------------------------------------------------------------------------
// Repack: weights -> MFMA B-fragment layout (f16); volume fp32 -> f16
// (volume branch: thread = one 8-elem unit, fully coalesced).
// ---------------------------------------------------------------------------
__global__ __launch_bounds__(256) void repack_kernel(
    const float* __restrict__ volume, const float* __restrict__ w_off,
    const float* __restrict__ w_dcn, short* __restrict__ ws)
{
    int idx = blockIdx.x * 256 + threadIdx.x;
    short* WB  = ws;
    short* WD  = ws + WB_ELEMS;
    short* V16 = ws + VOL16_OFF;
    if (idx < WB_ELEMS) {
        int j = idx & 7, l = (idx >> 3) & 63;
        int tn = idx >> 9;            // t*7 + n
        int n = tn % 7, t = tn / 7;
        int c = (l >> 4) * 8 + j;
        int oc = n * 16 + (l & 15);
        float v = (oc < OFFC) ? w_off[(t * CC + c) * OFFC + oc] : 0.f;
        WB[idx] = f2h(v);
    } else if (idx < WB_ELEMS + WD_ELEMS) {
        int idx2 = idx - WB_ELEMS;
        int j = idx2 & 7, l = (idx2 >> 3) & 63;
        int nt = idx2 >> 9;           // n*25 + t
        int t = nt % KT, n = nt / KT;
        int c = (l >> 4) * 8 + j;
        int f = n * 16 + (l & 15);
        WD[idx2] = f2h(w_dcn[(t * CC + c) * FF + f]);
    } else {
        int v = idx - (WB_ELEMS + WD_ELEMS);
        if (v < VOL_UNITS) {
            const float* src = volume + (size_t)v * 8;
            float4 q0 = *(const float4*)src;
            float4 q1 = *(const float4*)(src + 4);
            alignas(16) short tmp[8];
            tmp[0] = f2h(q0.x); tmp[1] = f2h(q0.y); tmp[2] = f2h(q0.z); tmp[3] = f2h(q0.w);
            tmp[4] = f2h(q1.x); tmp[5] = f2h(q1.y); tmp[6] = f2h(q1.z); tmp[7] = f2h(q1.w);
            *(s16x8*)&V16[(size_t)v * 8] = *(const s16x8*)tmp;
        }
    }
}

// ---------------------------------------------------------------------------
// Fused kernel: block = 32 px of one output row, 512 threads (8 waves).
//  P1: stage 9x40x32 f16 patch (swizzled, aliased over samp)
//  P2: offset GEMM (f16 MFMA, waves 0-6, 2 M-tiles) -> offtile (f16)
//  P3 [round-13 new]: 1600 (p,t,g) positions computed ONCE, packed 4B
//      {y0|x0<<7|wy9<<14|wx9<<23}, reg-staged, overwrites offtile region.
//  Four tap-quarters (7,6,6,6):
//   P4a: TLP gather: unit=(tap,g,px,cq); pos via broadcast ds_read_b32 +
//        ~8-op unpack (was ~30-op recompute, 4x redundant); 4 corner uint4
//        loads, pk-f16 combine, b128 store to xor-swizzled samp.
//   P4b: wave=(mt,ftile): ntap x (ds_read_b128 af + global wd + MFMA),
//        wrapped in s_setprio(1) (T5: blocks at different phases coexist).
// ---------------------------------------------------------------------------
__global__ __launch_bounds__(512, 4) void dcn_fused(
    const short* __restrict__ ws_ro, const float* __restrict__ b_off,
    const float* __restrict__ b_dcn, float* __restrict__ out)
{
    __shared__ __align__(16) char smem[35072];
    short* samp    = (short*)smem;             // 28,672 B: 7*32*8 units * 16B
    short* patch   = (short*)smem;             // 23,040 B (aliased, P1-P2 only)
    short* offtile = (short*)(smem + 28672);   //  6,400 B: [32 px][100] f16
    unsigned* posp = (unsigned*)(smem + 28672);//  6,400 B: [25][2][32] u32 (after P3)

    const short* WB  = ws_ro;
    const short* WD  = ws_ro + WB_ELEMS;
    const short* V16 = ws_ro + VOL16_OFF;

    const int tid  = threadIdx.x;
    const int lane = tid & 63;
    const int wv   = tid >> 6;
    const int ox0  = blockIdx.x * NPX;
    const int oy   = blockIdx.y;
    const int b    = blockIdx.z;
    const short* Vb = V16 + (size_t)b * (HH * WW * CC);

    // ---- P1: stage patch rows [oy,oy+9), cols [ox0,ox0+40) (col-clamped)
    for (int i = tid; i < 9 * 40 * 4; i += NTHREADS) {
        int cq = i & 3;
        int xi = (i >> 2) % 40;
        int yi = (i >> 2) / 40;
        int col = ox0 + xi; col = (col < WW) ? col : (WW - 1);
        s16x8 v = *(const s16x8*)&Vb[((size_t)(oy + yi) * WW + col) * CC + cq * 8];
        int u = ((yi * 40 + xi) << 2) + (cq ^ (xi & 3) ^ ((xi >> 2) & 3));
        *(s16x8*)&patch[u * 8] = v;
    }
    __syncthreads();

    // ---- P2: offset GEMM (f16). wave w<7 -> n-tile w, both M-tiles.
    if (wv < 7) {
        const int pr = lane & 15, cq = lane >> 4;
        f32x4 a0 = (f32x4){0.f, 0.f, 0.f, 0.f};
        f32x4 a1 = (f32x4){0.f, 0.f, 0.f, 0.f};
        for (int fh = 0; fh < 5; ++fh) {
            #pragma unroll
            for (int fw = 0; fw < 5; ++fw) {
                int t = fh * 5 + fw;
                int x0 = pr + 2 * fw, x1 = x0 + 16;
                f16x8 af0 = *(const f16x8*)&patch[((((2 * fh) * 40 + x0) << 2) + (cq ^ (x0 & 3) ^ ((x0 >> 2) & 3))) * 8];
                f16x8 af1 = *(const f16x8*)&patch[((((2 * fh) * 40 + x1) << 2) + (cq ^ (x1 & 3) ^ ((x1 >> 2) & 3))) * 8];
                f16x8 bf = *(const f16x8*)&WB[(t * 7 + wv) * 512 + lane * 8];
                a0 = __builtin_amdgcn_mfma_f32_16x16x32_f16(af0, bf, a0, 0, 0, 0);
                a1 = __builtin_amdgcn_mfma_f32_16x16x32_f16(af1, bf, a1, 0, 0, 0);
            }
        }
        int col = lane & 15, q = lane >> 4;
        int oc = wv * 16 + col;
        if (oc < OFFC) {
            float bo = b_off[oc];
            #pragma unroll
            for (int r = 0; r < 4; ++r) {
                offtile[(q * 4 + r) * 100 + oc]        = f2h(a0[r] + bo);
                offtile[(16 + q * 4 + r) * 100 + oc]   = f2h(a1[r] + bo);
            }
        }
    }
    __syncthreads();

    // ---- P3: positions once, packed 4B, reg-staged over offtile region.
    unsigned st0 = 0, st1 = 0, st2 = 0, st3 = 0;
    #pragma unroll
    for (int j = 0; j < 4; ++j) {
        int item = tid + j * NTHREADS;
        if (item < 1600) {
            int p = item & 31, g = (item >> 5) & 1, t = item >> 6;
            int pe = (ox0 + p < OW) ? p : (OW - 1 - ox0);
            int t5 = t / 5, tm5 = t - t5 * 5;
            float dy = h2f(offtile[pe * 100 + t * 4 + g]);
            float dx = h2f(offtile[pe * 100 + t * 4 + 2 + g]);
            float py = (float)(oy + 2 * t5) + dy;
            float px = (float)(ox0 + pe + 2 * tm5) + dx;
            py = fminf(fmaxf(py, 0.f), 127.f);
            px = fminf(fmaxf(px, 0.f), 127.f);
            float y0f = fminf(floorf(py), 126.f);
            float x0f = fminf(floorf(px), 126.f);
            unsigned wyq = (unsigned)((py - y0f) * 512.f + 0.5f);
            unsigned wxq = (unsigned)((px - x0f) * 512.f + 0.5f);
            wyq = wyq > 511u ? 511u : wyq;
            wxq = wxq > 511u ? 511u : wxq;
            unsigned pc = (unsigned)(int)y0f | ((unsigned)(int)x0f << 7)
                        | (wyq << 14) | (wxq << 23);
            if (j == 0) st0 = pc; else if (j == 1) st1 = pc;
            else if (j == 2) st2 = pc; else st3 = pc;
        }
    }
    __syncthreads();   // all offtile reads done
    #pragma unroll
    for (int j = 0; j < 4; ++j) {
        int item = tid + j * NTHREADS;
        if (item < 1600) {
            int p = item & 31, g = (item >> 5) & 1, t = item >> 6;
            unsigned pc = (j == 0) ? st0 : (j == 1) ? st1 : (j == 2) ? st2 : st3;
            posp[(t * 2 + g) * 32 + p] = pc;
        }
    }
    __syncthreads();

    // ---- tap quarters
    const int mt = wv & 1;            // M-tile (16 px)
    const int ft = wv >> 1;           // f-tile 0..3
    const int g_ = ft >> 1;           // deform group of this f-tile
    const int p_ = mt * 16 + (lane & 15);
    const int cq_ = lane >> 4;
    f32x4 acc = (f32x4){0.f, 0.f, 0.f, 0.f};

    for (int h = 0; h < 4; ++h) {
        const int tbase = (h == 0) ? 0 : (h == 1) ? 7 : (h == 2) ? 13 : 19;
        const int ntap  = (h == 0) ? 7 : 6;

        // P4a: gather. unit u: c=u&3, p=(u>>2)&31, g=(u>>7)&1, tp=u>>8
        for (int u = tid; u < ntap * 256; u += NTHREADS) {
            int c  = u & 3;
            int p  = (u >> 2) & 31;
            int gg = (u >> 7) & 1;
            int tp = u >> 8;
            int t  = tbase + tp;
            unsigned pc = posp[(t * 2 + gg) * 32 + p];   // 4-lane broadcast
            int y0  = pc & 127;
            int x0i = (pc >> 7) & 127;
            float wy = (float)((pc >> 14) & 511) * (1.f / 512.f);
            float wx = (float)(pc >> 23) * (1.f / 512.f);
            float w00 = (1.f - wy) * (1.f - wx);
            float w01 = (1.f - wy) * wx;
            float w10 = wy * (1.f - wx);
            float w11 = wy * wx;
            h2 W00 = (h2){(_Float16)w00, (_Float16)w00};
            h2 W01 = (h2){(_Float16)w01, (_Float16)w01};
            h2 W10 = (h2){(_Float16)w10, (_Float16)w10};
            h2 W11 = (h2){(_Float16)w11, (_Float16)w11};

            const short* vb0 = Vb + ((size_t)(y0 * WW + x0i)) * CC + c * 8;
            uint4 Au = *(const uint4*)(vb0);                 // v00, 8 ch
            uint4 Bu = *(const uint4*)(vb0 + CC);            // v01
            uint4 Cu = *(const uint4*)(vb0 + WW * CC);       // v10
            uint4 Du = *(const uint4*)(vb0 + WW * CC + CC);  // v11

            uint4 res;
            {
                h2 r0 = __builtin_bit_cast(h2, Au.x) * W00;
                r0 = __builtin_elementwise_fma(__builtin_bit_cast(h2, Bu.x), W01, r0);
                r0 = __builtin_elementwise_fma(__builtin_bit_cast(h2, Cu.x), W10, r0);
                r0 = __builtin_elementwise_fma(__builtin_bit_cast(h2, Du.x), W11, r0);
                res.x = __builtin_bit_cast(unsigned, r0);
                h2 r1 = __builtin_bit_cast(h2, Au.y) * W00;
                r1 = __builtin_elementwise_fma(__builtin_bit_cast(h2, Bu.y), W01, r1);
                r1 = __builtin_elementwise_fma(__builtin_bit_cast(h2, Cu.y), W10, r1);
                r1 = __builtin_elementwise_fma(__builtin_bit_cast(h2, Du.y), W11, r1);
                res.y = __builtin_bit_cast(unsigned, r1);
                h2 r2 = __builtin_bit_cast(h2, Au.z) * W00;
                r2 = __builtin_elementwise_fma(__builtin_bit_cast(h2, Bu.z), W01, r2);
                r2 = __builtin_elementwise_fma(__builtin_bit_cast(h2, Cu.z), W10, r2);
                r2 = __builtin_elementwise_fma(__builtin_bit_cast(h2, Du.z), W11, r2);
                res.z = __builtin_bit_cast(unsigned, r2);
                h2 r3 = __builtin_bit_cast(h2, Au.w) * W00;
                r3 = __builtin_elementwise_fma(__builtin_bit_cast(h2, Bu.w), W01, r3);
                r3 = __builtin_elementwise_fma(__builtin_bit_cast(h2, Cu.w), W10, r3);
                r3 = __builtin_elementwise_fma(__builtin_bit_cast(h2, Du.w), W11, r3);
                res.w = __builtin_bit_cast(unsigned, r3);
            }
            int unit = (tp * 32 + p) * 8 + ((gg * 4 + c) ^ (p & 7));
            *(uint4*)&samp[unit * 8] = res;
        }
        __syncthreads();

        // P4b: einsum for this quarter. wave (mt, ft), K = ntap taps x 32 ch.
        {
            const short* wd = WD + (ft * KT + tbase) * 512 + lane * 8;
            __builtin_amdgcn_s_setprio(1);
            for (int tp = 0; tp < ntap; ++tp) {
                int unit = (tp * 32 + p_) * 8 + ((g_ * 4 + cq_) ^ (p_ & 7));
                f16x8 af = *(const f16x8*)&samp[unit * 8];
                f16x8 bf = *(const f16x8*)&wd[tp * 512];
                acc = __builtin_amdgcn_mfma_f32_16x16x32_f16(af, bf, acc, 0, 0, 0);
            }
            __builtin_amdgcn_s_setprio(0);
        }
        __syncthreads();
    }

    // ---- epilogue: wave (mt, ft) owns 16px x 16f
    {
        int col = lane & 15, q = lane >> 4;
        int f = ft * 16 + col;
        float bd = b_dcn[f];
        long pix0 = ((long)b * OH + oy) * OW + ox0;
        #pragma unroll
        for (int r = 0; r < 4; ++r) {
            int pp = mt * 16 + q * 4 + r;
            if (ox0 + pp < OW)
                out[(pix0 + pp) * FF + f] = acc[r] + bd;
        }
    }
}

extern "C" void kernel_launch(void* const* d_in, const int* in_sizes, int n_in,
                              void* d_out, int out_size, void* d_ws, size_t ws_size,
                              hipStream_t stream) {
    const float* volume = (const float*)d_in[0];
    const float* w_off  = (const float*)d_in[1];
    const float* b_off  = (const float*)d_in[2];
    const float* w_dcn  = (const float*)d_in[3];
    const float* b_dcn  = (const float*)d_in[4];
    float* out = (float*)d_out;
    short* ws  = (short*)d_ws;   // 4.48 MB used

    int repack_threads = WB_ELEMS + WD_ELEMS + VOL_UNITS;   // 402,944
    int repack_blocks  = (repack_threads + 255) / 256;      // 1574
    repack_kernel<<<repack_blocks, 256, 0, stream>>>(volume, w_off, w_dcn, ws);

    dim3 g2((OW + NPX - 1) / NPX, OH, BB);   // 4 x 120 x 4 = 1920 blocks
    dcn_fused<<<g2, NTHREADS, 0, stream>>>(ws, b_off, b_dcn, out);
}